// Round 1
// baseline (3800.676 us; speedup 1.0000x reference)
//
#include <hip/hip_runtime.h>
#include <math.h>

#define N_NODES 50000
#define N_EDGES 1000000
#define CCH     32
#define ROW     288   // 32 + 96 + 160

// ---------------------------------------------------------------------------
// Edge kernel: 32 lanes per edge (lane = channel c), 8 edges per 256-thr block.
// Each lane redundantly computes the tiny MLP hidden chain (8->6->6->6),
// then its 3 final-layer outputs (w0[c], w1[c], w2[c]), gathers x[sender][c],
// and scatter-adds its 9 message components into msg[receiver].
// ---------------------------------------------------------------------------
__global__ __launch_bounds__(256) void edge_kernel(
    const float* __restrict__ lenght,        // (E, 8)
    const float* __restrict__ node_features, // (N, 32)
    const float* __restrict__ edge_attr,     // (E, 9)
    const int*   __restrict__ edge_index,    // (2, E)
    const float* __restrict__ fw0,           // (8, 6)
    const float* __restrict__ fw1,           // (6, 6)
    const float* __restrict__ fw2,           // (6, 6)
    const float* __restrict__ fw3,           // (6, 96)
    float*       __restrict__ msg)           // (N, 288) accumulator
{
    __shared__ float s_w[48 + 36 + 36 + 576];   // fcn weights, 696 floats
    for (int i = threadIdx.x; i < 696; i += 256) {
        float v;
        if (i < 48)       v = fw0[i];
        else if (i < 84)  v = fw1[i - 48];
        else if (i < 120) v = fw2[i - 84];
        else              v = fw3[i - 120];
        s_w[i] = v;
    }
    __syncthreads();
    const float* sw0 = s_w;
    const float* sw1 = s_w + 48;
    const float* sw2 = s_w + 84;
    const float* sw3 = s_w + 120;

    const int c = threadIdx.x & 31;
    const int e = blockIdx.x * 8 + (threadIdx.x >> 5);   // grid covers E exactly

    const float inv8 = 0.35355339059327373f;   // 1/sqrt(8)
    const float inv6 = 0.4082482904638631f;    // 1/sqrt(6)

    // --- tiny MLP (redundant per lane; ~120 MACs) ---
    float len[8];
    #pragma unroll
    for (int k = 0; k < 8; ++k) len[k] = lenght[(long long)e * 8 + k];

    float h0[6], h1[6], h2[6];
    #pragma unroll
    for (int j = 0; j < 6; ++j) {
        float a = 0.f;
        #pragma unroll
        for (int k = 0; k < 8; ++k) a += len[k] * sw0[k * 6 + j];
        a *= inv8;
        h0[j] = a / (1.f + __expf(-a));        // silu
    }
    #pragma unroll
    for (int j = 0; j < 6; ++j) {
        float a = 0.f;
        #pragma unroll
        for (int k = 0; k < 6; ++k) a += h0[k] * sw1[k * 6 + j];
        a *= inv6;
        h1[j] = a / (1.f + __expf(-a));
    }
    #pragma unroll
    for (int j = 0; j < 6; ++j) {
        float a = 0.f;
        #pragma unroll
        for (int k = 0; k < 6; ++k) a += h1[k] * sw2[k * 6 + j];
        a *= inv6;
        h2[j] = a / (1.f + __expf(-a));
    }

    // --- final layer: this lane's 3 outputs ---
    float w0c = 0.f, w1c = 0.f, w2c = 0.f;
    #pragma unroll
    for (int k = 0; k < 6; ++k) {
        const float h = h2[k];
        w0c += h * sw3[k * 96 + c];
        w1c += h * sw3[k * 96 + 32 + c];
        w2c += h * sw3[k * 96 + 64 + c];
    }
    w0c *= inv6; w1c *= inv6; w2c *= inv6;

    // --- gather + message + scatter ---
    const int s = edge_index[e];
    const int r = edge_index[N_EDGES + e];
    const float x = node_features[(long long)s * CCH + c];
    const float* ea = edge_attr + (long long)e * 9;

    float* mrow = msg + (long long)r * ROW;
    atomicAdd(&mrow[c], w0c * x * ea[0]);

    const float a1 = w1c * x;
    #pragma unroll
    for (int i = 0; i < 3; ++i)
        atomicAdd(&mrow[32 + c * 3 + i], a1 * ea[1 + i]);

    const float a2 = w2c * x;
    #pragma unroll
    for (int i = 0; i < 5; ++i)
        atomicAdd(&mrow[128 + c * 5 + i], a2 * ea[4 + i]);
}

// ---------------------------------------------------------------------------
// Node kernel: 8 nodes per 256-thr block (lane = output channel d).
// msg rows staged in LDS; per-lane reads of m[...] are group-broadcast
// (address independent of d) -> conflict-free; weight reads coalesced over d.
// ---------------------------------------------------------------------------
__global__ __launch_bounds__(256) void node_kernel(
    const float* __restrict__ msg,   // (N, 288)
    const float* __restrict__ lw0,   // (32, 32)
    const float* __restrict__ lw1,   // (32, 32)
    const float* __restrict__ lw2,   // (32, 32)
    float*       __restrict__ out)   // (N, 288)
{
    __shared__ float s_msg[8 * ROW];
    const int n0 = blockIdx.x * 8;   // 50000/8 = 6250 blocks exactly
    for (int i = threadIdx.x; i < 8 * ROW; i += 256)
        s_msg[i] = msg[(long long)n0 * ROW + i];
    __syncthreads();

    const int d  = threadIdx.x & 31;
    const int ln = threadIdx.x >> 5;
    const float* m = s_msg + ln * ROW;
    float* o = out + (long long)(n0 + ln) * ROW;
    const float inv32 = 0.17677669529663687f;  // 1/sqrt(32)

    float acc0 = 0.f;
    float a1[3] = {0.f, 0.f, 0.f};
    float a2[5] = {0.f, 0.f, 0.f, 0.f, 0.f};
    for (int c = 0; c < 32; ++c) {
        acc0 += m[c] * lw0[c * 32 + d];
        const float w1 = lw1[c * 32 + d];
        #pragma unroll
        for (int i = 0; i < 3; ++i) a1[i] += m[32 + c * 3 + i] * w1;
        const float w2 = lw2[c * 32 + d];
        #pragma unroll
        for (int i = 0; i < 5; ++i) a2[i] += m[128 + c * 5 + i] * w2;
    }

    o[d] = acc0 * inv32;
    #pragma unroll
    for (int i = 0; i < 3; ++i) o[32 + d * 3 + i] = a1[i] * inv32;
    #pragma unroll
    for (int i = 0; i < 5; ++i) o[128 + d * 5 + i] = a2[i] * inv32;
}

extern "C" void kernel_launch(void* const* d_in, const int* in_sizes, int n_in,
                              void* d_out, int out_size, void* d_ws, size_t ws_size,
                              hipStream_t stream)
{
    const float* lenght = (const float*)d_in[0];
    const float* nf     = (const float*)d_in[1];
    const float* ea     = (const float*)d_in[2];
    const int*   ei     = (const int*)d_in[3];
    const float* fw0    = (const float*)d_in[4];
    const float* fw1    = (const float*)d_in[5];
    const float* fw2    = (const float*)d_in[6];
    const float* fw3    = (const float*)d_in[7];
    const float* lw0    = (const float*)d_in[8];
    const float* lw1    = (const float*)d_in[9];
    const float* lw2    = (const float*)d_in[10];
    float* out = (float*)d_out;
    float* msgbuf = (float*)d_ws;   // N_NODES*288 floats = 57.6 MB

    hipMemsetAsync(msgbuf, 0, (size_t)N_NODES * ROW * sizeof(float), stream);

    edge_kernel<<<N_EDGES / 8, 256, 0, stream>>>(
        lenght, nf, ea, ei, fw0, fw1, fw2, fw3, msgbuf);

    node_kernel<<<N_NODES / 8, 256, 0, stream>>>(
        msgbuf, lw0, lw1, lw2, out);
}

// Round 2
// 568.705 us; speedup vs baseline: 6.6830x; 6.6830x over previous
//
#include <hip/hip_runtime.h>
#include <math.h>

#define N_NODES 50000
#define N_EDGES 1000000
#define CCH     32
#define ROW     288   // 32 + 96 + 160

// ---------------------------------------------------------------------------
// K0: per-edge MLP hidden chain (8->6->6->6 with silu). One thread per edge.
// Writes h2 (6 floats/edge, 24 MB) so the gather kernel only needs the final
// 6->96 layer (18 MACs per lane) instead of the full redundant chain.
// ---------------------------------------------------------------------------
__global__ __launch_bounds__(256) void mlp_kernel(
    const float* __restrict__ lenght,  // (E, 8)
    const float* __restrict__ fw0,     // (8, 6)
    const float* __restrict__ fw1,     // (6, 6)
    const float* __restrict__ fw2,     // (6, 6)
    float*       __restrict__ h2buf)   // (E, 6)
{
    __shared__ float s_w[120];
    for (int i = threadIdx.x; i < 120; i += 256)
        s_w[i] = (i < 48) ? fw0[i] : (i < 84) ? fw1[i - 48] : fw2[i - 84];
    __syncthreads();
    const float* sw0 = s_w;
    const float* sw1 = s_w + 48;
    const float* sw2 = s_w + 84;

    const int e = blockIdx.x * 256 + threadIdx.x;
    if (e >= N_EDGES) return;

    const float inv8 = 0.35355339059327373f;   // 1/sqrt(8)
    const float inv6 = 0.4082482904638631f;    // 1/sqrt(6)

    float len[8];
    const float4 l0 = ((const float4*)(lenght + (long long)e * 8))[0];
    const float4 l1 = ((const float4*)(lenght + (long long)e * 8))[1];
    len[0]=l0.x; len[1]=l0.y; len[2]=l0.z; len[3]=l0.w;
    len[4]=l1.x; len[5]=l1.y; len[6]=l1.z; len[7]=l1.w;

    float h0[6], h1[6], h2[6];
    #pragma unroll
    for (int j = 0; j < 6; ++j) {
        float a = 0.f;
        #pragma unroll
        for (int k = 0; k < 8; ++k) a += len[k] * sw0[k * 6 + j];
        a *= inv8;
        h0[j] = a / (1.f + __expf(-a));
    }
    #pragma unroll
    for (int j = 0; j < 6; ++j) {
        float a = 0.f;
        #pragma unroll
        for (int k = 0; k < 6; ++k) a += h0[k] * sw1[k * 6 + j];
        a *= inv6;
        h1[j] = a / (1.f + __expf(-a));
    }
    #pragma unroll
    for (int j = 0; j < 6; ++j) {
        float a = 0.f;
        #pragma unroll
        for (int k = 0; k < 6; ++k) a += h1[k] * sw2[k * 6 + j];
        a *= inv6;
        h2[j] = a / (1.f + __expf(-a));
    }
    #pragma unroll
    for (int j = 0; j < 6; ++j) h2buf[(long long)e * 6 + j] = h2[j];
}

// ---------------------------------------------------------------------------
// K1: degree histogram over receivers.
// ---------------------------------------------------------------------------
__global__ __launch_bounds__(256) void hist_kernel(
    const int* __restrict__ edge_index, int* __restrict__ deg)
{
    const int e = blockIdx.x * 256 + threadIdx.x;
    if (e >= N_EDGES) return;
    atomicAdd(&deg[edge_index[N_EDGES + e]], 1);
}

// ---------------------------------------------------------------------------
// K2: single-block exclusive scan of deg[50000] -> offset, cursor.
// 1024 threads x 49 elements each: serial sum, Hillis-Steele block scan,
// serial write-back.
// ---------------------------------------------------------------------------
__global__ __launch_bounds__(1024) void scan_kernel(
    const int* __restrict__ deg, int* __restrict__ offset, int* __restrict__ cursor)
{
    __shared__ int s[1024];
    const int t = threadIdx.x;
    const int lo = t * 49;
    const int hi = (lo + 49 < N_NODES) ? lo + 49 : N_NODES;
    int sum = 0;
    for (int i = lo; i < hi; ++i) sum += deg[i];
    s[t] = sum;
    __syncthreads();
    for (int ofs = 1; ofs < 1024; ofs <<= 1) {
        int v = (t >= ofs) ? s[t - ofs] : 0;
        __syncthreads();
        s[t] += v;
        __syncthreads();
    }
    int base = s[t] - sum;   // exclusive prefix
    for (int i = lo; i < hi; ++i) {
        offset[i] = base;
        cursor[i] = base;
        base += deg[i];
    }
}

// ---------------------------------------------------------------------------
// K3: scatter edge ids into CSR order.
// ---------------------------------------------------------------------------
__global__ __launch_bounds__(256) void scatter_kernel(
    const int* __restrict__ edge_index, int* __restrict__ cursor,
    int* __restrict__ sorted_eid)
{
    const int e = blockIdx.x * 256 + threadIdx.x;
    if (e >= N_EDGES) return;
    const int r = edge_index[N_EDGES + e];
    const int p = atomicAdd(&cursor[r], 1);
    sorted_eid[p] = e;
}

// ---------------------------------------------------------------------------
// K4: fused gather + message + segment-sum + node linear.
// One 64-lane wave per node; half-wave h processes edges j = h, h+2, ...
// lane = channel c. Accumulate 9 message floats per channel in registers,
// combine halves via shfl, LDS round-trip, then the three 32x32 linears
// (c-loop split across halves), combine, write 288 outputs.
// ---------------------------------------------------------------------------
__global__ __launch_bounds__(256) void gather_kernel(
    const float* __restrict__ h2buf,        // (E, 6)
    const float* __restrict__ node_features,// (N, 32)
    const float* __restrict__ edge_attr,    // (E, 9)
    const int*   __restrict__ edge_index,   // (2, E) [0]=sender
    const int*   __restrict__ sorted_eid,   // (E)
    const int*   __restrict__ offset,       // (N)
    const int*   __restrict__ deg,          // (N)
    const float* __restrict__ fw3,          // (6, 96)
    const float* __restrict__ lw0,          // (32, 32)
    const float* __restrict__ lw1,          // (32, 32)
    const float* __restrict__ lw2,          // (32, 32)
    float*       __restrict__ out)          // (N, 288)
{
    __shared__ float s_fw3[576];
    __shared__ float s_m[4][ROW];           // per-wave msg row, layout [c*9 + k]
    for (int i = threadIdx.x; i < 576; i += 256) s_fw3[i] = fw3[i];
    __syncthreads();

    const int wave = threadIdx.x >> 6;
    const int l    = threadIdx.x & 63;
    const int c    = l & 31;
    const int h    = l >> 5;
    const int node = blockIdx.x * 4 + wave;     // 12500 blocks exact

    const float inv6  = 0.4082482904638631f;    // 1/sqrt(6)
    const float inv32 = 0.17677669529663687f;   // 1/sqrt(32)

    const int off = offset[node];
    const int dg  = deg[node];

    float acc0 = 0.f;
    float acc1[3] = {0.f, 0.f, 0.f};
    float acc2[5] = {0.f, 0.f, 0.f, 0.f, 0.f};

    for (int j = h; j < dg; j += 2) {
        const int eid = sorted_eid[off + j];

        // final MLP layer: this lane's 3 weights
        const float* hp = h2buf + (long long)eid * 6;
        float w0c = 0.f, w1c = 0.f, w2c = 0.f;
        #pragma unroll
        for (int k = 0; k < 6; ++k) {
            const float hv = hp[k];
            w0c += hv * s_fw3[k * 96 + c];
            w1c += hv * s_fw3[k * 96 + 32 + c];
            w2c += hv * s_fw3[k * 96 + 64 + c];
        }

        const int snd = edge_index[eid];
        const float x = node_features[(long long)snd * CCH + c];
        const float* ea = edge_attr + (long long)eid * 9;

        acc0 += (w0c * inv6) * x * ea[0];
        const float a1 = (w1c * inv6) * x;
        #pragma unroll
        for (int i = 0; i < 3; ++i) acc1[i] += a1 * ea[1 + i];
        const float a2 = (w2c * inv6) * x;
        #pragma unroll
        for (int i = 0; i < 5; ++i) acc2[i] += a2 * ea[4 + i];
    }

    // combine the two halves (results land in lanes 0..31)
    acc0 += __shfl_down(acc0, 32);
    #pragma unroll
    for (int i = 0; i < 3; ++i) acc1[i] += __shfl_down(acc1[i], 32);
    #pragma unroll
    for (int i = 0; i < 5; ++i) acc2[i] += __shfl_down(acc2[i], 32);

    if (h == 0) {
        float* m = s_m[wave] + c * 9;
        m[0] = acc0;
        #pragma unroll
        for (int i = 0; i < 3; ++i) m[1 + i] = acc1[i];
        #pragma unroll
        for (int i = 0; i < 5; ++i) m[4 + i] = acc2[i];
    }
    __syncthreads();

    // node linear: lane d = c, halves split the channel loop
    const float* m = s_m[wave];
    const int d = c;
    float o0 = 0.f;
    float o1[3] = {0.f, 0.f, 0.f};
    float o2[5] = {0.f, 0.f, 0.f, 0.f, 0.f};
    for (int cc = h * 16; cc < h * 16 + 16; ++cc) {
        const float* mc = m + cc * 9;
        o0 += mc[0] * lw0[cc * 32 + d];
        const float w1 = lw1[cc * 32 + d];
        #pragma unroll
        for (int i = 0; i < 3; ++i) o1[i] += mc[1 + i] * w1;
        const float w2 = lw2[cc * 32 + d];
        #pragma unroll
        for (int i = 0; i < 5; ++i) o2[i] += mc[4 + i] * w2;
    }

    o0 += __shfl_down(o0, 32);
    #pragma unroll
    for (int i = 0; i < 3; ++i) o1[i] += __shfl_down(o1[i], 32);
    #pragma unroll
    for (int i = 0; i < 5; ++i) o2[i] += __shfl_down(o2[i], 32);

    if (h == 0) {
        float* op = out + (long long)node * ROW;
        op[d] = o0 * inv32;
        #pragma unroll
        for (int i = 0; i < 3; ++i) op[32 + d * 3 + i] = o1[i] * inv32;
        #pragma unroll
        for (int i = 0; i < 5; ++i) op[128 + d * 5 + i] = o2[i] * inv32;
    }
}

extern "C" void kernel_launch(void* const* d_in, const int* in_sizes, int n_in,
                              void* d_out, int out_size, void* d_ws, size_t ws_size,
                              hipStream_t stream)
{
    const float* lenght = (const float*)d_in[0];
    const float* nf     = (const float*)d_in[1];
    const float* ea     = (const float*)d_in[2];
    const int*   ei     = (const int*)d_in[3];
    const float* fw0    = (const float*)d_in[4];
    const float* fw1    = (const float*)d_in[5];
    const float* fw2    = (const float*)d_in[6];
    const float* fw3    = (const float*)d_in[7];
    const float* lw0    = (const float*)d_in[8];
    const float* lw1    = (const float*)d_in[9];
    const float* lw2    = (const float*)d_in[10];
    float* out = (float*)d_out;

    // workspace layout
    char* ws = (char*)d_ws;
    float* h2buf      = (float*)ws;                       ws += (size_t)N_EDGES * 6 * sizeof(float);  // 24 MB
    int*   deg        = (int*)ws;                         ws += (size_t)N_NODES * sizeof(int);
    int*   offset     = (int*)ws;                         ws += (size_t)N_NODES * sizeof(int);
    int*   cursor     = (int*)ws;                         ws += (size_t)N_NODES * sizeof(int);
    int*   sorted_eid = (int*)ws;                         ws += (size_t)N_EDGES * sizeof(int);

    hipMemsetAsync(deg, 0, (size_t)N_NODES * sizeof(int), stream);

    const int EB = (N_EDGES + 255) / 256;
    mlp_kernel    <<<EB, 256, 0, stream>>>(lenght, fw0, fw1, fw2, h2buf);
    hist_kernel   <<<EB, 256, 0, stream>>>(ei, deg);
    scan_kernel   <<<1, 1024, 0, stream>>>(deg, offset, cursor);
    scatter_kernel<<<EB, 256, 0, stream>>>(ei, cursor, sorted_eid);
    gather_kernel <<<N_NODES / 4, 256, 0, stream>>>(
        h2buf, nf, ea, ei, sorted_eid, offset, deg,
        fw3, lw0, lw1, lw2, out);
}

// Round 3
// 480.976 us; speedup vs baseline: 7.9020x; 1.1824x over previous
//
#include <hip/hip_runtime.h>
#include <math.h>

#define N_NODES 50000
#define N_EDGES 1000000
#define CCH     32
#define ROW     288   // 32 + 96 + 160

// ---------------------------------------------------------------------------
// K1: degree histogram over receivers.
// ---------------------------------------------------------------------------
__global__ __launch_bounds__(256) void hist_kernel(
    const int* __restrict__ edge_index, int* __restrict__ deg)
{
    const int e = blockIdx.x * 256 + threadIdx.x;
    if (e >= N_EDGES) return;
    atomicAdd(&deg[edge_index[N_EDGES + e]], 1);
}

// ---------------------------------------------------------------------------
// K2: single-block exclusive scan of deg[50000] -> offset, cursor.
// ---------------------------------------------------------------------------
__global__ __launch_bounds__(1024) void scan_kernel(
    const int* __restrict__ deg, int* __restrict__ offset, int* __restrict__ cursor)
{
    __shared__ int s[1024];
    const int t = threadIdx.x;
    const int lo = t * 49;
    const int hi = (lo + 49 < N_NODES) ? lo + 49 : N_NODES;
    int sum = 0;
    for (int i = lo; i < hi; ++i) sum += deg[i];
    s[t] = sum;
    __syncthreads();
    for (int ofs = 1; ofs < 1024; ofs <<= 1) {
        int v = (t >= ofs) ? s[t - ofs] : 0;
        __syncthreads();
        s[t] += v;
        __syncthreads();
    }
    int base = s[t] - sum;   // exclusive prefix
    for (int i = lo; i < hi; ++i) {
        offset[i] = base;
        cursor[i] = base;
        base += deg[i];
    }
}

// ---------------------------------------------------------------------------
// K3: fused MLP + pack into CSR order. One thread per edge, all input reads
// sequential/coalesced. Writes one 64-B record per edge at its CSR slot:
//   [ h2*inv6 (6) | y0 (1) | y1 (3) | y2 (5) | sender-as-bits (1) ]
// ---------------------------------------------------------------------------
__global__ __launch_bounds__(256) void pack_kernel(
    const float* __restrict__ lenght,     // (E, 8)
    const float* __restrict__ edge_attr,  // (E, 9)
    const int*   __restrict__ edge_index, // (2, E)
    const float* __restrict__ fw0,        // (8, 6)
    const float* __restrict__ fw1,        // (6, 6)
    const float* __restrict__ fw2,        // (6, 6)
    int*         __restrict__ cursor,     // (N)
    float4*      __restrict__ rec)        // (E, 4 x float4)
{
    __shared__ float s_w[120];
    for (int i = threadIdx.x; i < 120; i += 256)
        s_w[i] = (i < 48) ? fw0[i] : (i < 84) ? fw1[i - 48] : fw2[i - 84];
    __syncthreads();
    const float* sw0 = s_w;
    const float* sw1 = s_w + 48;
    const float* sw2 = s_w + 84;

    const int e = blockIdx.x * 256 + threadIdx.x;
    if (e >= N_EDGES) return;

    const float inv8 = 0.35355339059327373f;   // 1/sqrt(8)
    const float inv6 = 0.4082482904638631f;    // 1/sqrt(6)

    float len[8];
    const float4 l0 = ((const float4*)(lenght + (long long)e * 8))[0];
    const float4 l1 = ((const float4*)(lenght + (long long)e * 8))[1];
    len[0]=l0.x; len[1]=l0.y; len[2]=l0.z; len[3]=l0.w;
    len[4]=l1.x; len[5]=l1.y; len[6]=l1.z; len[7]=l1.w;

    float h0[6], h1[6], h2[6];
    #pragma unroll
    for (int j = 0; j < 6; ++j) {
        float a = 0.f;
        #pragma unroll
        for (int k = 0; k < 8; ++k) a += len[k] * sw0[k * 6 + j];
        a *= inv8;
        h0[j] = a / (1.f + __expf(-a));
    }
    #pragma unroll
    for (int j = 0; j < 6; ++j) {
        float a = 0.f;
        #pragma unroll
        for (int k = 0; k < 6; ++k) a += h0[k] * sw1[k * 6 + j];
        a *= inv6;
        h1[j] = a / (1.f + __expf(-a));
    }
    #pragma unroll
    for (int j = 0; j < 6; ++j) {
        float a = 0.f;
        #pragma unroll
        for (int k = 0; k < 6; ++k) a += h1[k] * sw2[k * 6 + j];
        a *= inv6;
        h2[j] = a * inv6 / (1.f + __expf(-a));   // fold final-layer 1/sqrt(6)
    }

    const float* ea = edge_attr + (long long)e * 9;
    float y[9];
    #pragma unroll
    for (int i = 0; i < 9; ++i) y[i] = ea[i];

    const int snd = edge_index[e];
    const int r   = edge_index[N_EDGES + e];
    const int p   = atomicAdd(&cursor[r], 1);

    float4* rp = rec + (long long)p * 4;
    rp[0] = make_float4(h2[0], h2[1], h2[2], h2[3]);
    rp[1] = make_float4(h2[4], h2[5], y[0], y[1]);
    rp[2] = make_float4(y[2], y[3], y[4], y[5]);
    rp[3] = make_float4(y[6], y[7], y[8], __int_as_float(snd));
}

// ---------------------------------------------------------------------------
// K4: gather + message + segment-sum + node linear. One 64-lane wave / node,
// no LDS, no barriers. Half-wave h handles edges j = h, h+2, ...; lane = c.
// Records are read sequentially (CSR order) with 1-deep prefetch. The
// msg(c)->linear(d) transpose is done with __shfl.
// ---------------------------------------------------------------------------
__global__ __launch_bounds__(256) void gather_kernel(
    const float4* __restrict__ rec,          // (E, 4 x float4)
    const float*  __restrict__ node_features,// (N, 32)
    const int*    __restrict__ offset,       // (N)
    const int*    __restrict__ deg,          // (N)
    const float*  __restrict__ fw3,          // (6, 96)
    const float*  __restrict__ lw0,          // (32, 32)
    const float*  __restrict__ lw1,          // (32, 32)
    const float*  __restrict__ lw2,          // (32, 32)
    float*        __restrict__ out)          // (N, 288)
{
    const int wave = threadIdx.x >> 6;
    const int l    = threadIdx.x & 63;
    const int c    = l & 31;
    const int h    = l >> 5;
    const int node = blockIdx.x * 4 + wave;     // 12500 blocks exact

    // this lane's three fw3 columns, in registers
    float f3a[6], f3b[6], f3c[6];
    #pragma unroll
    for (int k = 0; k < 6; ++k) {
        f3a[k] = fw3[k * 96 + c];
        f3b[k] = fw3[k * 96 + 32 + c];
        f3c[k] = fw3[k * 96 + 64 + c];
    }

    const int off = offset[node];
    const int dg  = deg[node];

    float acc[9] = {0.f,0.f,0.f,0.f,0.f,0.f,0.f,0.f,0.f};

    int j = h;
    float4 r0, r1, r2, r3;
    if (j < dg) {
        const float4* rp = rec + (long long)(off + j) * 4;
        r0 = rp[0]; r1 = rp[1]; r2 = rp[2]; r3 = rp[3];
    }
    while (j < dg) {
        const int jn = j + 2;
        float4 n0, n1, n2, n3;
        if (jn < dg) {                              // prefetch next record
            const float4* rp = rec + (long long)(off + jn) * 4;
            n0 = rp[0]; n1 = rp[1]; n2 = rp[2]; n3 = rp[3];
        }
        const int snd = __float_as_int(r3.w);
        const float x = node_features[(long long)snd * CCH + c];

        const float w0c = r0.x*f3a[0] + r0.y*f3a[1] + r0.z*f3a[2]
                        + r0.w*f3a[3] + r1.x*f3a[4] + r1.y*f3a[5];
        const float w1c = r0.x*f3b[0] + r0.y*f3b[1] + r0.z*f3b[2]
                        + r0.w*f3b[3] + r1.x*f3b[4] + r1.y*f3b[5];
        const float w2c = r0.x*f3c[0] + r0.y*f3c[1] + r0.z*f3c[2]
                        + r0.w*f3c[3] + r1.x*f3c[4] + r1.y*f3c[5];

        acc[0] += (w0c * x) * r1.z;
        const float a1 = w1c * x;
        acc[1] += a1 * r1.w;
        acc[2] += a1 * r2.x;
        acc[3] += a1 * r2.y;
        const float a2 = w2c * x;
        acc[4] += a2 * r2.z;
        acc[5] += a2 * r2.w;
        acc[6] += a2 * r3.x;
        acc[7] += a2 * r3.y;
        acc[8] += a2 * r3.z;

        r0 = n0; r1 = n1; r2 = n2; r3 = n3;
        j = jn;
    }

    // combine halves: lanes 0..31 end up holding msg[c][0..8]
    #pragma unroll
    for (int k = 0; k < 9; ++k) acc[k] += __shfl_down(acc[k], 32);

    // node linear via shfl transpose; lane d = c, halves split the cc loop
    const int d = c;
    float o0 = 0.f;
    float o1[3] = {0.f, 0.f, 0.f};
    float o2[5] = {0.f, 0.f, 0.f, 0.f, 0.f};
    for (int cc = h * 16; cc < h * 16 + 16; ++cc) {
        const float m0 = __shfl(acc[0], cc);
        const float m1 = __shfl(acc[1], cc);
        const float m2 = __shfl(acc[2], cc);
        const float m3 = __shfl(acc[3], cc);
        const float m4 = __shfl(acc[4], cc);
        const float m5 = __shfl(acc[5], cc);
        const float m6 = __shfl(acc[6], cc);
        const float m7 = __shfl(acc[7], cc);
        const float m8 = __shfl(acc[8], cc);
        o0 += m0 * lw0[cc * 32 + d];
        const float w1 = lw1[cc * 32 + d];
        o1[0] += m1 * w1; o1[1] += m2 * w1; o1[2] += m3 * w1;
        const float w2 = lw2[cc * 32 + d];
        o2[0] += m4 * w2; o2[1] += m5 * w2; o2[2] += m6 * w2;
        o2[3] += m7 * w2; o2[4] += m8 * w2;
    }

    o0 += __shfl_down(o0, 32);
    #pragma unroll
    for (int i = 0; i < 3; ++i) o1[i] += __shfl_down(o1[i], 32);
    #pragma unroll
    for (int i = 0; i < 5; ++i) o2[i] += __shfl_down(o2[i], 32);

    if (h == 0) {
        const float inv32 = 0.17677669529663687f;  // 1/sqrt(32)
        float* op = out + (long long)node * ROW;
        op[d] = o0 * inv32;
        #pragma unroll
        for (int i = 0; i < 3; ++i) op[32 + d * 3 + i] = o1[i] * inv32;
        #pragma unroll
        for (int i = 0; i < 5; ++i) op[128 + d * 5 + i] = o2[i] * inv32;
    }
}

extern "C" void kernel_launch(void* const* d_in, const int* in_sizes, int n_in,
                              void* d_out, int out_size, void* d_ws, size_t ws_size,
                              hipStream_t stream)
{
    const float* lenght = (const float*)d_in[0];
    const float* nf     = (const float*)d_in[1];
    const float* ea     = (const float*)d_in[2];
    const int*   ei     = (const int*)d_in[3];
    const float* fw0    = (const float*)d_in[4];
    const float* fw1    = (const float*)d_in[5];
    const float* fw2    = (const float*)d_in[6];
    const float* fw3    = (const float*)d_in[7];
    const float* lw0    = (const float*)d_in[8];
    const float* lw1    = (const float*)d_in[9];
    const float* lw2    = (const float*)d_in[10];
    float* out = (float*)d_out;

    // workspace layout
    char* ws = (char*)d_ws;
    float4* rec   = (float4*)ws;  ws += (size_t)N_EDGES * 4 * sizeof(float4);  // 64 MB
    int* deg      = (int*)ws;     ws += (size_t)N_NODES * sizeof(int);
    int* offset   = (int*)ws;     ws += (size_t)N_NODES * sizeof(int);
    int* cursor   = (int*)ws;     ws += (size_t)N_NODES * sizeof(int);

    hipMemsetAsync(deg, 0, (size_t)N_NODES * sizeof(int), stream);

    const int EB = (N_EDGES + 255) / 256;
    hist_kernel<<<EB, 256, 0, stream>>>(ei, deg);
    scan_kernel<<<1, 1024, 0, stream>>>(deg, offset, cursor);
    pack_kernel<<<EB, 256, 0, stream>>>(lenght, ea, ei, fw0, fw1, fw2, cursor, rec);
    gather_kernel<<<N_NODES / 4, 256, 0, stream>>>(
        rec, nf, offset, deg, fw3, lw0, lw1, lw2, out);
}

// Round 5
// 381.775 us; speedup vs baseline: 9.9553x; 1.2598x over previous
//
#include <hip/hip_runtime.h>
#include <math.h>

#define N_NODES 50000
#define N_EDGES 1000000
#define CCH     32
#define ROW     288           // 32 + 96 + 160
#define SCAN_BLOCKS 196       // ceil(50000/256)

// ---------------------------------------------------------------------------
// K1: degree histogram over receivers.
// ---------------------------------------------------------------------------
__global__ __launch_bounds__(256) void hist_kernel(
    const int* __restrict__ edge_index, int* __restrict__ deg)
{
    const int e = blockIdx.x * 256 + threadIdx.x;
    if (e >= N_EDGES) return;
    atomicAdd(&deg[edge_index[N_EDGES + e]], 1);
}

// ---------------------------------------------------------------------------
// K2a: per-block scan of deg. Writes local exclusive prefix + block sums.
// ---------------------------------------------------------------------------
__global__ __launch_bounds__(256) void scan_local_kernel(
    const int* __restrict__ deg, int* __restrict__ lexcl, int* __restrict__ blocksum)
{
    __shared__ int s[256];
    const int t = threadIdx.x;
    const int gid = blockIdx.x * 256 + t;
    const int v = (gid < N_NODES) ? deg[gid] : 0;
    s[t] = v;
    __syncthreads();
    for (int ofs = 1; ofs < 256; ofs <<= 1) {
        int w = (t >= ofs) ? s[t - ofs] : 0;
        __syncthreads();
        s[t] += w;
        __syncthreads();
    }
    if (gid < N_NODES) lexcl[gid] = s[t] - v;
    if (t == 255) blocksum[blockIdx.x] = s[255];
}

// ---------------------------------------------------------------------------
// K2b: one tiny block scans the 196 block sums -> exclusive block prefixes.
// ---------------------------------------------------------------------------
__global__ __launch_bounds__(256) void scan_top_kernel(
    const int* __restrict__ blocksum, int* __restrict__ blockpref)
{
    __shared__ int s[256];
    const int t = threadIdx.x;
    const int v = (t < SCAN_BLOCKS) ? blocksum[t] : 0;
    s[t] = v;
    __syncthreads();
    for (int ofs = 1; ofs < 256; ofs <<= 1) {
        int w = (t >= ofs) ? s[t - ofs] : 0;
        __syncthreads();
        s[t] += w;
        __syncthreads();
    }
    if (t < SCAN_BLOCKS) blockpref[t] = s[t] - v;
}

// ---------------------------------------------------------------------------
// K2c: offset[i] = cursor[i] = blockpref[block] + lexcl[i]
// ---------------------------------------------------------------------------
__global__ __launch_bounds__(256) void scan_addback_kernel(
    const int* __restrict__ lexcl, const int* __restrict__ blockpref,
    int* __restrict__ offset, int* __restrict__ cursor)
{
    const int gid = blockIdx.x * 256 + threadIdx.x;
    if (gid >= N_NODES) return;
    const int base = blockpref[blockIdx.x] + lexcl[gid];
    offset[gid] = base;
    cursor[gid] = base;
}

// ---------------------------------------------------------------------------
// K3: fused MLP + pack into CSR order. One thread per edge, all input reads
// sequential/coalesced. Writes one 64-B record per edge at its CSR slot:
//   [ h2*inv6 (6) | y0 (1) | y1 (3) | y2 (5) | sender-as-bits (1) ]
// ---------------------------------------------------------------------------
__global__ __launch_bounds__(256) void pack_kernel(
    const float* __restrict__ lenght,     // (E, 8)
    const float* __restrict__ edge_attr,  // (E, 9)
    const int*   __restrict__ edge_index, // (2, E)
    const float* __restrict__ fw0,        // (8, 6)
    const float* __restrict__ fw1,        // (6, 6)
    const float* __restrict__ fw2,        // (6, 6)
    int*         __restrict__ cursor,     // (N)
    float4*      __restrict__ rec)        // (E, 4 x float4)
{
    __shared__ float s_w[120];
    for (int i = threadIdx.x; i < 120; i += 256)
        s_w[i] = (i < 48) ? fw0[i] : (i < 84) ? fw1[i - 48] : fw2[i - 84];
    __syncthreads();
    const float* sw0 = s_w;
    const float* sw1 = s_w + 48;
    const float* sw2 = s_w + 84;

    const int e = blockIdx.x * 256 + threadIdx.x;
    if (e >= N_EDGES) return;

    const float inv8 = 0.35355339059327373f;   // 1/sqrt(8)
    const float inv6 = 0.4082482904638631f;    // 1/sqrt(6)

    float len[8];
    const float4 l0 = ((const float4*)(lenght + (long long)e * 8))[0];
    const float4 l1 = ((const float4*)(lenght + (long long)e * 8))[1];
    len[0]=l0.x; len[1]=l0.y; len[2]=l0.z; len[3]=l0.w;
    len[4]=l1.x; len[5]=l1.y; len[6]=l1.z; len[7]=l1.w;

    float h0[6], h1[6], h2[6];
    #pragma unroll
    for (int j = 0; j < 6; ++j) {
        float a = 0.f;
        #pragma unroll
        for (int k = 0; k < 8; ++k) a += len[k] * sw0[k * 6 + j];
        a *= inv8;
        h0[j] = a / (1.f + __expf(-a));
    }
    #pragma unroll
    for (int j = 0; j < 6; ++j) {
        float a = 0.f;
        #pragma unroll
        for (int k = 0; k < 6; ++k) a += h0[k] * sw1[k * 6 + j];
        a *= inv6;
        h1[j] = a / (1.f + __expf(-a));
    }
    #pragma unroll
    for (int j = 0; j < 6; ++j) {
        float a = 0.f;
        #pragma unroll
        for (int k = 0; k < 6; ++k) a += h1[k] * sw2[k * 6 + j];
        a *= inv6;
        h2[j] = a * inv6 / (1.f + __expf(-a));   // fold final-layer 1/sqrt(6)
    }

    const float* ea = edge_attr + (long long)e * 9;
    float y[9];
    #pragma unroll
    for (int i = 0; i < 9; ++i) y[i] = ea[i];

    const int snd = edge_index[e];
    const int r   = edge_index[N_EDGES + e];
    const int p   = atomicAdd(&cursor[r], 1);

    float4* rp = rec + (long long)p * 4;
    rp[0] = make_float4(h2[0], h2[1], h2[2], h2[3]);
    rp[1] = make_float4(h2[4], h2[5], y[0], y[1]);
    rp[2] = make_float4(y[2], y[3], y[4], y[5]);
    rp[3] = make_float4(y[6], y[7], y[8], __int_as_float(snd));
}

// ---------------------------------------------------------------------------
// K4: gather + message + segment-sum + node linear. One 64-lane wave / node,
// no barriers in the main loop. Half-wave h handles edges j = h, h+2, ...;
// lane = c. Records read sequentially with 1-deep prefetch; x issued as soon
// as its record arrives and consumed after the 18-FMA w-block. lw in LDS.
// ---------------------------------------------------------------------------
__global__ __launch_bounds__(256) void gather_kernel(
    const float4* __restrict__ rec,          // (E, 4 x float4)
    const float*  __restrict__ node_features,// (N, 32)
    const int*    __restrict__ offset,       // (N)
    const int*    __restrict__ deg,          // (N)
    const float*  __restrict__ fw3,          // (6, 96)
    const float*  __restrict__ lw0,          // (32, 32)
    const float*  __restrict__ lw1,          // (32, 32)
    const float*  __restrict__ lw2,          // (32, 32)
    float*        __restrict__ out)          // (N, 288)
{
    __shared__ float s_lw0[1024], s_lw1[1024], s_lw2[1024];
    for (int i = threadIdx.x; i < 1024; i += 256) {
        s_lw0[i] = lw0[i];
        s_lw1[i] = lw1[i];
        s_lw2[i] = lw2[i];
    }
    __syncthreads();

    const int wave = threadIdx.x >> 6;
    const int l    = threadIdx.x & 63;
    const int c    = l & 31;
    const int h    = l >> 5;
    const int node = blockIdx.x * 4 + wave;     // 12500 blocks exact

    float f3a[6], f3b[6], f3c[6];
    #pragma unroll
    for (int k = 0; k < 6; ++k) {
        f3a[k] = fw3[k * 96 + c];
        f3b[k] = fw3[k * 96 + 32 + c];
        f3c[k] = fw3[k * 96 + 64 + c];
    }

    const int off = offset[node];
    const int dg  = deg[node];

    float acc[9] = {0.f,0.f,0.f,0.f,0.f,0.f,0.f,0.f,0.f};

    int j = h;
    float4 r0, r1, r2, r3;
    float  xq = 0.f;
    if (j < dg) {
        const float4* rp = rec + (long long)(off + j) * 4;
        r0 = rp[0]; r1 = rp[1]; r2 = rp[2]; r3 = rp[3];
        xq = node_features[(long long)__float_as_int(r3.w) * CCH + c];
    }
    while (j < dg) {
        const int jn = j + 2;
        float4 n0, n1, n2, n3;
        if (jn < dg) {                              // prefetch next record
            const float4* rp = rec + (long long)(off + jn) * 4;
            n0 = rp[0]; n1 = rp[1]; n2 = rp[2]; n3 = rp[3];
        }

        // w-computation needs only the record -> overlaps xq latency
        const float w0c = r0.x*f3a[0] + r0.y*f3a[1] + r0.z*f3a[2]
                        + r0.w*f3a[3] + r1.x*f3a[4] + r1.y*f3a[5];
        const float w1c = r0.x*f3b[0] + r0.y*f3b[1] + r0.z*f3b[2]
                        + r0.w*f3b[3] + r1.x*f3b[4] + r1.y*f3b[5];
        const float w2c = r0.x*f3c[0] + r0.y*f3c[1] + r0.z*f3c[2]
                        + r0.w*f3c[3] + r1.x*f3c[4] + r1.y*f3c[5];

        const float x = xq;                         // waitcnt lands here
        acc[0] += (w0c * x) * r1.z;
        const float a1 = w1c * x;
        acc[1] += a1 * r1.w;
        acc[2] += a1 * r2.x;
        acc[3] += a1 * r2.y;
        const float a2 = w2c * x;
        acc[4] += a2 * r2.z;
        acc[5] += a2 * r2.w;
        acc[6] += a2 * r3.x;
        acc[7] += a2 * r3.y;
        acc[8] += a2 * r3.z;

        if (jn < dg)                                // issue next x ASAP
            xq = node_features[(long long)__float_as_int(n3.w) * CCH + c];
        r0 = n0; r1 = n1; r2 = n2; r3 = n3;
        j = jn;
    }

    // combine halves: lanes 0..31 hold msg[c][0..8]
    #pragma unroll
    for (int k = 0; k < 9; ++k) acc[k] += __shfl_down(acc[k], 32);

    // node linear via shfl transpose; lane d = c, halves split the cc loop
    const int d = c;
    float o0 = 0.f;
    float o1[3] = {0.f, 0.f, 0.f};
    float o2[5] = {0.f, 0.f, 0.f, 0.f, 0.f};
    for (int cc = h * 16; cc < h * 16 + 16; ++cc) {
        const float m0 = __shfl(acc[0], cc);
        const float m1 = __shfl(acc[1], cc);
        const float m2 = __shfl(acc[2], cc);
        const float m3 = __shfl(acc[3], cc);
        const float m4 = __shfl(acc[4], cc);
        const float m5 = __shfl(acc[5], cc);
        const float m6 = __shfl(acc[6], cc);
        const float m7 = __shfl(acc[7], cc);
        const float m8 = __shfl(acc[8], cc);
        o0 += m0 * s_lw0[cc * 32 + d];
        const float w1 = s_lw1[cc * 32 + d];
        o1[0] += m1 * w1; o1[1] += m2 * w1; o1[2] += m3 * w1;
        const float w2 = s_lw2[cc * 32 + d];
        o2[0] += m4 * w2; o2[1] += m5 * w2; o2[2] += m6 * w2;
        o2[3] += m7 * w2; o2[4] += m8 * w2;
    }

    o0 += __shfl_down(o0, 32);
    #pragma unroll
    for (int i = 0; i < 3; ++i) o1[i] += __shfl_down(o1[i], 32);
    #pragma unroll
    for (int i = 0; i < 5; ++i) o2[i] += __shfl_down(o2[i], 32);

    if (h == 0) {
        const float inv32 = 0.17677669529663687f;  // 1/sqrt(32)
        float* op = out + (long long)node * ROW;
        op[d] = o0 * inv32;
        #pragma unroll
        for (int i = 0; i < 3; ++i) op[32 + d * 3 + i] = o1[i] * inv32;
        #pragma unroll
        for (int i = 0; i < 5; ++i) op[128 + d * 5 + i] = o2[i] * inv32;
    }
}

extern "C" void kernel_launch(void* const* d_in, const int* in_sizes, int n_in,
                              void* d_out, int out_size, void* d_ws, size_t ws_size,
                              hipStream_t stream)
{
    const float* lenght = (const float*)d_in[0];
    const float* nf     = (const float*)d_in[1];
    const float* ea     = (const float*)d_in[2];
    const int*   ei     = (const int*)d_in[3];
    const float* fw0    = (const float*)d_in[4];
    const float* fw1    = (const float*)d_in[5];
    const float* fw2    = (const float*)d_in[6];
    const float* fw3    = (const float*)d_in[7];
    const float* lw0    = (const float*)d_in[8];
    const float* lw1    = (const float*)d_in[9];
    const float* lw2    = (const float*)d_in[10];
    float* out = (float*)d_out;

    // workspace layout
    char* ws = (char*)d_ws;
    float4* rec    = (float4*)ws; ws += (size_t)N_EDGES * 4 * sizeof(float4);  // 64 MB
    int* deg       = (int*)ws;    ws += (size_t)N_NODES * sizeof(int);
    int* offset    = (int*)ws;    ws += (size_t)N_NODES * sizeof(int);
    int* cursor    = (int*)ws;    ws += (size_t)N_NODES * sizeof(int);
    int* lexcl     = (int*)ws;    ws += (size_t)N_NODES * sizeof(int);
    int* blocksum  = (int*)ws;    ws += (size_t)SCAN_BLOCKS * sizeof(int);
    int* blockpref = (int*)ws;    ws += (size_t)SCAN_BLOCKS * sizeof(int);

    hipMemsetAsync(deg, 0, (size_t)N_NODES * sizeof(int), stream);

    const int EB = (N_EDGES + 255) / 256;
    hist_kernel        <<<EB, 256, 0, stream>>>(ei, deg);
    scan_local_kernel  <<<SCAN_BLOCKS, 256, 0, stream>>>(deg, lexcl, blocksum);
    scan_top_kernel    <<<1, 256, 0, stream>>>(blocksum, blockpref);
    scan_addback_kernel<<<SCAN_BLOCKS, 256, 0, stream>>>(lexcl, blockpref, offset, cursor);
    pack_kernel        <<<EB, 256, 0, stream>>>(lenght, ea, ei, fw0, fw1, fw2, cursor, rec);
    gather_kernel      <<<N_NODES / 4, 256, 0, stream>>>(
        rec, nf, offset, deg, fw3, lw0, lw1, lw2, out);
}